// Round 1
// baseline (370.390 us; speedup 1.0000x reference)
//
#include <hip/hip_runtime.h>

namespace {
constexpr int N_ = 64, C_ = 512, P_ = 900, K_ = 64;
constexpr size_t AT_ELEMS = (size_t)N_ * P_ * K_;   // a' [N][P][K] : 3,686,400 floats
constexpr size_t ASUM_OFF = AT_ELEMS;               // asum [N][K] : 4096 floats
constexpr size_t WT_OFF   = ASUM_OFF + (size_t)N_ * K_;  // wt [C][K] : 32768 floats
}

// --- transpose conv_w [K][C] -> wt [C][K] so phase1 reads contiguous, wave-uniform rows
__global__ __launch_bounds__(256) void k_transpose_w(const float* __restrict__ w,
                                                     float* __restrict__ wt) {
  int idx = blockIdx.x * 256 + threadIdx.x;
  if (idx < C_ * K_) {
    int c = idx >> 6, k = idx & 63;
    wt[idx] = w[k * C_ + c];
  }
}

// --- phase 1: per (n,p): sumsq + d[k] = sum_c x*w in one pass; softmax over k;
//     write a' = a * inv_norm to at[n][p][k]; accumulate asum[n][k] (raw a).
//     Thread layout: 256 threads = 128 p-slots x 2 k-halves (32 k each).
__global__ __launch_bounds__(256) void k_phase1(const float* __restrict__ x,
                                                const float* __restrict__ wt,
                                                float* __restrict__ at,
                                                float* __restrict__ asum) {
  __shared__ float Ld[128][66];  // logits exchange, padded vs bank conflicts
  const int n  = blockIdx.y;
  const int pl = threadIdx.x & 127;
  const int kh = threadIdx.x >> 7;            // 0 or 1
  const int p  = blockIdx.x * 128 + pl;
  const bool active = p < P_;
  const float* xp = x + (size_t)n * C_ * P_ + (active ? p : 0);
  const float* wcol = wt + kh * 32;

  float d[32];
  #pragma unroll
  for (int i = 0; i < 32; ++i) d[i] = 0.f;
  float sumsq = 0.f;
  for (int c = 0; c < C_; ++c) {
    float xv = active ? xp[(size_t)c * P_] : 0.f;
    sumsq = fmaf(xv, xv, sumsq);
    const float* wr = wcol + c * K_;          // wave-uniform -> scalar loads
    #pragma unroll
    for (int i = 0; i < 32; ++i) d[i] = fmaf(xv, wr[i], d[i]);
  }
  const float invd = 1.f / fmaxf(sqrtf(sumsq), 1e-12f);

  #pragma unroll
  for (int i = 0; i < 32; ++i) Ld[pl][kh * 32 + i] = d[i] * invd;
  __syncthreads();
  float m = -1e30f;
  #pragma unroll 8
  for (int j = 0; j < 64; ++j) m = fmaxf(m, Ld[pl][j]);
  float s = 0.f;
  #pragma unroll 8
  for (int j = 0; j < 64; ++j) s += __expf(Ld[pl][j] - m);
  const float invs = 1.f / s;

  float a[32];
  #pragma unroll
  for (int i = 0; i < 32; ++i)
    a[i] = active ? __expf(d[i] * invd - m) * invs : 0.f;

  if (active) {
    float* atp = at + ((size_t)n * P_ + p) * K_ + kh * 32;
    #pragma unroll
    for (int i = 0; i < 32; i += 4) {
      float4 v = make_float4(a[i] * invd, a[i+1] * invd, a[i+2] * invd, a[i+3] * invd);
      *reinterpret_cast<float4*>(atp + i) = v;
    }
  }

  // asum[n][k] += sum over p: wave shuffle-reduce then one atomic per wave per k
  const int lane = threadIdx.x & 63;
  #pragma unroll
  for (int i = 0; i < 32; ++i) {
    float v = a[i];
    #pragma unroll
    for (int off = 32; off > 0; off >>= 1) v += __shfl_xor(v, off, 64);
    if (lane == 0) atomicAdd(asum + n * K_ + kh * 32 + i, v);
  }
}

// --- phase 2: vlad[n][k][c] = sum_p a'[n][k? p][k] * x[n][c][p] - asum[n][k]*cent[k][c]
//     Block: one n, 128-wide c tile, all 64 k. P in 15 chunks of 60.
__global__ __launch_bounds__(256) void k_phase2(const float* __restrict__ x,
                                                const float* __restrict__ at,
                                                const float* __restrict__ asum,
                                                const float* __restrict__ cent,
                                                float* __restrict__ out) {
  __shared__ float Xl[60][132];   // [j][c], padded stride for conflict-free b128
  __shared__ float Al[60][64];    // [j][k]
  const int n  = blockIdx.y;
  const int c0 = blockIdx.x * 128;
  const int tid = threadIdx.x;
  const int cq = (tid & 31) * 4;  // 4 consecutive c per thread
  const int kg = tid >> 5;        // 8 k per thread: k = kg*8 + u

  float acc[8][4];
  #pragma unroll
  for (int u = 0; u < 8; ++u)
    #pragma unroll
    for (int i = 0; i < 4; ++i) acc[u][i] = 0.f;

  for (int ch = 0; ch < 15; ++ch) {
    const int pb = ch * 60;
    // X tile: read float4 along p, transpose into Xl[j][c]
    for (int idx = tid; idx < 128 * 15; idx += 256) {
      const int c = idx / 15, jq = idx - c * 15;
      const float4 v = *reinterpret_cast<const float4*>(
          x + ((size_t)n * C_ + c0 + c) * P_ + pb + jq * 4);
      Xl[jq*4+0][c] = v.x; Xl[jq*4+1][c] = v.y;
      Xl[jq*4+2][c] = v.z; Xl[jq*4+3][c] = v.w;
    }
    // A tile: at is [n][p][k] so rows are contiguous in k — direct b128 copy
    for (int idx = tid; idx < 60 * 16; idx += 256) {
      const int j = idx >> 4, kq = idx & 15;
      *reinterpret_cast<float4*>(&Al[j][kq * 4]) =
          *reinterpret_cast<const float4*>(at + ((size_t)n * P_ + pb + j) * K_ + kq * 4);
    }
    __syncthreads();
    #pragma unroll 4
    for (int j = 0; j < 60; ++j) {
      const float4 xq = *reinterpret_cast<const float4*>(&Xl[j][cq]);
      const float4 a0 = *reinterpret_cast<const float4*>(&Al[j][kg * 8]);
      const float4 a1 = *reinterpret_cast<const float4*>(&Al[j][kg * 8 + 4]);
      const float xs[4] = {xq.x, xq.y, xq.z, xq.w};
      const float as8[8] = {a0.x, a0.y, a0.z, a0.w, a1.x, a1.y, a1.z, a1.w};
      #pragma unroll
      for (int u = 0; u < 8; ++u)
        #pragma unroll
        for (int i = 0; i < 4; ++i)
          acc[u][i] = fmaf(as8[u], xs[i], acc[u][i]);
    }
    __syncthreads();
  }

  #pragma unroll
  for (int u = 0; u < 8; ++u) {
    const int k = kg * 8 + u;
    const float av = asum[n * K_ + k];
    const float4 cv = *reinterpret_cast<const float4*>(cent + k * C_ + c0 + cq);
    float4 o;
    o.x = fmaf(-av, cv.x, acc[u][0]);
    o.y = fmaf(-av, cv.y, acc[u][1]);
    o.z = fmaf(-av, cv.z, acc[u][2]);
    o.w = fmaf(-av, cv.w, acc[u][3]);
    *reinterpret_cast<float4*>(out + ((size_t)(n * K_ + k)) * C_ + c0 + cq) = o;
  }
}

extern "C" void kernel_launch(void* const* d_in, const int* in_sizes, int n_in,
                              void* d_out, int out_size, void* d_ws, size_t ws_size,
                              hipStream_t stream) {
  const float* x    = (const float*)d_in[0];
  const float* w    = (const float*)d_in[1];
  const float* cent = (const float*)d_in[2];
  float* out  = (float*)d_out;
  float* ws   = (float*)d_ws;
  float* at   = ws;
  float* asum = ws + ASUM_OFF;
  float* wt   = ws + WT_OFF;

  hipMemsetAsync(asum, 0, (size_t)N_ * K_ * sizeof(float), stream);
  k_transpose_w<<<dim3(128), dim3(256), 0, stream>>>(w, wt);
  k_phase1<<<dim3(8, 64), dim3(256), 0, stream>>>(x, wt, at, asum);
  k_phase2<<<dim3(4, 64), dim3(256), 0, stream>>>(x, at, asum, cent, out);
}

// Round 2
// 194.621 us; speedup vs baseline: 1.9031x; 1.9031x over previous
//
#include <hip/hip_runtime.h>

namespace {
constexpr int N_ = 64, C_ = 512, P_ = 900, K_ = 64;
constexpr size_t TOT_X = (size_t)N_ * C_ * P_;       // 117,964,800 floats
constexpr size_t AT_ELEMS = (size_t)N_ * P_ * K_;    // a' [N][P][K]
constexpr size_t ASUM_OFF = AT_ELEMS;                // asum [N][K]
constexpr size_t WT_OFF   = ASUM_OFF + (size_t)N_ * K_;  // wt [C][K]
}

// --- transpose conv_w [K][C] -> wt [C][K]
__global__ __launch_bounds__(256) void k_transpose_w(const float* __restrict__ w,
                                                     float* __restrict__ wt) {
  int idx = blockIdx.x * 256 + threadIdx.x;
  if (idx < C_ * K_) {
    int c = idx >> 6, k = idx & 63;
    wt[idx] = w[k * C_ + c];
  }
}

// --- phase 1 (LDS-tiled GEMM + fused norm + maxless softmax):
//     block = (n, 128-p tile), all 64 k, c in 16 tiles of 32.
//     thread: 4 consecutive p x 8 k. Writes a' = a*inv_norm to at[n][p][k],
//     atomics raw-a sums into asum[n][k].
__global__ __launch_bounds__(256) void k_phase1(const float* __restrict__ x,
                                                const float* __restrict__ wt,
                                                float* __restrict__ at,
                                                float* __restrict__ asum) {
  __shared__ float Xl[32][132];  // [c][p] padded (528B rows, 16B-aligned)
  __shared__ float Wl[32][64];   // [c][k]
  __shared__ float Ps[128][9];   // per-p partial softmax sums, padded

  const int n   = blockIdx.y;
  const int p0  = blockIdx.x * 128;
  const int tid = threadIdx.x;
  const int pq  = (tid & 31) * 4;   // p offset within tile (4 consecutive)
  const int kg  = tid >> 5;         // 8 k per thread: k = kg*8 + u

  float acc[8][4];
  #pragma unroll
  for (int u = 0; u < 8; ++u)
    #pragma unroll
    for (int i = 0; i < 4; ++i) acc[u][i] = 0.f;
  float ssq[4] = {0.f, 0.f, 0.f, 0.f};

  for (int ct = 0; ct < 16; ++ct) {
    const int c0 = ct * 32;
    // X tile: [32 c][128 p] floats = 1024 float4; coalesced along p.
    #pragma unroll
    for (int it = 0; it < 4; ++it) {
      const int idx = tid + it * 256;
      const int c = idx >> 5, pj = (idx & 31) * 4;
      size_t off = ((size_t)n * C_ + c0 + c) * P_ + p0 + pj;
      if (off > TOT_X - 4) off = TOT_X - 4;   // tail-safe clamp
      *reinterpret_cast<float4*>(&Xl[c][pj]) =
          *reinterpret_cast<const float4*>(x + off);
    }
    // W tile: [32 c][64 k] = 512 float4; contiguous.
    #pragma unroll
    for (int it = 0; it < 2; ++it) {
      const int idx = tid + it * 256;
      const int c = idx >> 4, k4 = (idx & 15) * 4;
      *reinterpret_cast<float4*>(&Wl[c][k4]) =
          *reinterpret_cast<const float4*>(wt + (size_t)(c0 + c) * K_ + k4);
    }
    __syncthreads();
    #pragma unroll 8
    for (int j = 0; j < 32; ++j) {
      const float4 xv = *reinterpret_cast<const float4*>(&Xl[j][pq]);
      const float4 w0 = *reinterpret_cast<const float4*>(&Wl[j][kg * 8]);
      const float4 w1 = *reinterpret_cast<const float4*>(&Wl[j][kg * 8 + 4]);
      const float xs[4] = {xv.x, xv.y, xv.z, xv.w};
      const float ws[8] = {w0.x, w0.y, w0.z, w0.w, w1.x, w1.y, w1.z, w1.w};
      #pragma unroll
      for (int i = 0; i < 4; ++i) ssq[i] = fmaf(xs[i], xs[i], ssq[i]);
      #pragma unroll
      for (int u = 0; u < 8; ++u)
        #pragma unroll
        for (int i = 0; i < 4; ++i)
          acc[u][i] = fmaf(ws[u], xs[i], acc[u][i]);
    }
    __syncthreads();
  }

  // inv_norm per p (each of the 8 kg-threads for a p computed identical ssq)
  float invd[4];
  #pragma unroll
  for (int i = 0; i < 4; ++i)
    invd[i] = 1.f / fmaxf(sqrtf(ssq[i]), 1e-12f);

  // exp (|logit| <= ||w_k||2 ~= 0.45 -> no max subtraction needed)
  float psum[4] = {0.f, 0.f, 0.f, 0.f};
  #pragma unroll
  for (int u = 0; u < 8; ++u)
    #pragma unroll
    for (int i = 0; i < 4; ++i) {
      acc[u][i] = __expf(acc[u][i] * invd[i]);
      psum[i] += acc[u][i];
    }
  #pragma unroll
  for (int i = 0; i < 4; ++i) Ps[pq + i][kg] = psum[i];
  __syncthreads();

  float invs[4];
  #pragma unroll
  for (int i = 0; i < 4; ++i) {
    float s = 0.f;
    #pragma unroll
    for (int g = 0; g < 8; ++g) s += Ps[pq + i][g];
    invs[i] = 1.f / s;
  }

  // write a' = a * invd; accumulate raw a into asum
  bool pv[4];
  #pragma unroll
  for (int i = 0; i < 4; ++i) pv[i] = (p0 + pq + i) < P_;

  #pragma unroll
  for (int i = 0; i < 4; ++i) {
    if (pv[i]) {
      float* atp = at + ((size_t)n * P_ + p0 + pq + i) * K_ + kg * 8;
      const float sc = invs[i] * invd[i];
      float4 v0 = make_float4(acc[0][i]*sc, acc[1][i]*sc, acc[2][i]*sc, acc[3][i]*sc);
      float4 v1 = make_float4(acc[4][i]*sc, acc[5][i]*sc, acc[6][i]*sc, acc[7][i]*sc);
      *reinterpret_cast<float4*>(atp)     = v0;
      *reinterpret_cast<float4*>(atp + 4) = v1;
    }
  }

  const int lane = threadIdx.x & 63;
  #pragma unroll
  for (int u = 0; u < 8; ++u) {
    float v = 0.f;
    #pragma unroll
    for (int i = 0; i < 4; ++i)
      v += pv[i] ? acc[u][i] * invs[i] : 0.f;
    // reduce across the 32-lane p-group (xor offsets stay within half-wave)
    #pragma unroll
    for (int off = 16; off > 0; off >>= 1) v += __shfl_xor(v, off, 64);
    if ((lane & 31) == 0) atomicAdd(asum + n * K_ + kg * 8 + u, v);
  }
}

// --- phase 2: vlad[n][k][c] = sum_p a'[n][p][k] * x[n][c][p] - asum[n][k]*cent[k][c]
__global__ __launch_bounds__(256) void k_phase2(const float* __restrict__ x,
                                                const float* __restrict__ at,
                                                const float* __restrict__ asum,
                                                const float* __restrict__ cent,
                                                float* __restrict__ out) {
  __shared__ float Xl[60][132];   // [j][c]
  __shared__ float Al[60][64];    // [j][k]
  const int n  = blockIdx.y;
  const int c0 = blockIdx.x * 128;
  const int tid = threadIdx.x;
  const int cq = (tid & 31) * 4;
  const int kg = tid >> 5;

  float acc[8][4];
  #pragma unroll
  for (int u = 0; u < 8; ++u)
    #pragma unroll
    for (int i = 0; i < 4; ++i) acc[u][i] = 0.f;

  for (int ch = 0; ch < 15; ++ch) {
    const int pb = ch * 60;
    for (int idx = tid; idx < 128 * 15; idx += 256) {
      const int c = idx / 15, jq = idx - c * 15;
      const float4 v = *reinterpret_cast<const float4*>(
          x + ((size_t)n * C_ + c0 + c) * P_ + pb + jq * 4);
      Xl[jq*4+0][c] = v.x; Xl[jq*4+1][c] = v.y;
      Xl[jq*4+2][c] = v.z; Xl[jq*4+3][c] = v.w;
    }
    for (int idx = tid; idx < 60 * 16; idx += 256) {
      const int j = idx >> 4, kq = idx & 15;
      *reinterpret_cast<float4*>(&Al[j][kq * 4]) =
          *reinterpret_cast<const float4*>(at + ((size_t)n * P_ + pb + j) * K_ + kq * 4);
    }
    __syncthreads();
    #pragma unroll 4
    for (int j = 0; j < 60; ++j) {
      const float4 xq = *reinterpret_cast<const float4*>(&Xl[j][cq]);
      const float4 a0 = *reinterpret_cast<const float4*>(&Al[j][kg * 8]);
      const float4 a1 = *reinterpret_cast<const float4*>(&Al[j][kg * 8 + 4]);
      const float xs[4] = {xq.x, xq.y, xq.z, xq.w};
      const float as8[8] = {a0.x, a0.y, a0.z, a0.w, a1.x, a1.y, a1.z, a1.w};
      #pragma unroll
      for (int u = 0; u < 8; ++u)
        #pragma unroll
        for (int i = 0; i < 4; ++i)
          acc[u][i] = fmaf(as8[u], xs[i], acc[u][i]);
    }
    __syncthreads();
  }

  #pragma unroll
  for (int u = 0; u < 8; ++u) {
    const int k = kg * 8 + u;
    const float av = asum[n * K_ + k];
    const float4 cv = *reinterpret_cast<const float4*>(cent + k * C_ + c0 + cq);
    float4 o;
    o.x = fmaf(-av, cv.x, acc[u][0]);
    o.y = fmaf(-av, cv.y, acc[u][1]);
    o.z = fmaf(-av, cv.z, acc[u][2]);
    o.w = fmaf(-av, cv.w, acc[u][3]);
    *reinterpret_cast<float4*>(out + ((size_t)(n * K_ + k)) * C_ + c0 + cq) = o;
  }
}

extern "C" void kernel_launch(void* const* d_in, const int* in_sizes, int n_in,
                              void* d_out, int out_size, void* d_ws, size_t ws_size,
                              hipStream_t stream) {
  const float* x    = (const float*)d_in[0];
  const float* w    = (const float*)d_in[1];
  const float* cent = (const float*)d_in[2];
  float* out  = (float*)d_out;
  float* ws   = (float*)d_ws;
  float* at   = ws;
  float* asum = ws + ASUM_OFF;
  float* wt   = ws + WT_OFF;

  hipMemsetAsync(asum, 0, (size_t)N_ * K_ * sizeof(float), stream);
  k_transpose_w<<<dim3(128), dim3(256), 0, stream>>>(w, wt);
  k_phase1<<<dim3(8, 64), dim3(256), 0, stream>>>(x, wt, at, asum);
  k_phase2<<<dim3(4, 64), dim3(256), 0, stream>>>(x, at, asum, cent, out);
}